// Round 3
// baseline (354.748 us; speedup 1.0000x reference)
//
#include <hip/hip_runtime.h>
#include <math.h>

#define EPS 1e-8f
#define LAMBDA 1e-3f

__device__ __forceinline__ float redsum32(float v) {
  #pragma unroll
  for (int off = 16; off >= 1; off >>= 1) v += __shfl_xor(v, off, 32);
  return v;
}
__device__ __forceinline__ float redmax32(float v) {
  #pragma unroll
  for (int off = 16; off >= 1; off >>= 1) v = fmaxf(v, __shfl_xor(v, off, 32));
  return v;
}

// One block per output row n (508 rows). 512 threads = 16 chunks x 32 c.
// Thread (chunk,c) owns output capsule c for B in [chunk*18, chunk*18+18).
// su = sum_c(r*a) == a exactly (softmax sums to 1) -> fold into af=a/(a+EPS).
// Cross-chunk reduction is two-phase (A1+S, then A2 reusing the buffer) to
// keep LDS <= ~44 KB -> 3 blocks/CU (24 waves/CU).
__launch_bounds__(512, 6)
__global__ void convcaps_kernel(const float* __restrict__ x,
                                const float* __restrict__ wgl,
                                const float* __restrict__ beta_u,
                                const float* __restrict__ beta_a,
                                float* __restrict__ out) {
  __shared__ float xr[288][16];       // pose patches, 18 KB
  __shared__ float a_sh[288];         // a/(a+EPS)
  __shared__ float red[17][256];      // two-phase reduction scratch, 17.4 KB
  __shared__ float mu_l[32][17];      // +1 pad
  __shared__ float i2s_l[32][17];     // 1/(2*sigma)
  __shared__ float hl_l[32][17];      // 0.5*ln(sigma)
  __shared__ float S_l[32];
  __shared__ float aout_l[32];
  __shared__ float lnao_l[32];

  const int tid = threadIdx.x;
  const int n = blockIdx.x;
  const int c = tid & 31;
  const int chunk = tid >> 5;         // 0..15

  // ---- stage 9 source rows (float4): xr[B][s], a_sh[B]=a/(a+EPS) ----
  for (int idx = tid; idx < 1224; idx += 512) {   // 9 * 136 float4
    int t = idx / 136;
    int e4 = idx - t * 136;
    int g = 9 * n + t;
    int bg = g / 2286;                 // 2286 = 9*254
    int ki = (g % 2286) / 762;         // 762 = 3*254
    int owp = g % 254;
    const float4* src = reinterpret_cast<const float4*>(x) +
                        (size_t)((bg * 256 + ki + owp) * 4) * 136;
    float4 val = src[e4];
    if (e4 < 128) {
      reinterpret_cast<float4*>(&xr[0][0])[t * 128 + e4] = val;
    } else {
      val.x = val.x / (val.x + EPS);
      val.y = val.y / (val.y + EPS);
      val.z = val.z / (val.z + EPS);
      val.w = val.w / (val.w + EPS);
      reinterpret_cast<float4*>(a_sh)[t * 8 + (e4 - 128)] = val;
    }
  }
  __syncthreads();

  float A1[16], A2[16], Ssum;
  float mu[16], i2s[16];
  const size_t rbase = 276352;         // 2*254*544

  for (int pass = 0; pass < 3; ++pass) {
    #pragma unroll
    for (int s = 0; s < 16; ++s) { A1[s] = 0.f; A2[s] = 0.f; }
    Ssum = 0.f;
    float bias = 0.f;
    if (pass > 0) {
      float Hl = 0.f;
      #pragma unroll
      for (int s = 0; s < 16; ++s) {
        mu[s] = mu_l[c][s];
        i2s[s] = i2s_l[c][s];
        Hl += hl_l[c][s];
      }
      bias = lnao_l[c] - Hl;
    }

    for (int i = 0; i < 18; ++i) {
      int B = chunk * 18 + i;
      const float4* wp = reinterpret_cast<const float4*>(wgl + ((size_t)(B * 32 + c)) * 16);
      float4 w0 = wp[0], w1 = wp[1], w2 = wp[2], w3 = wp[3];
      const float4* xp = reinterpret_cast<const float4*>(&xr[B][0]);
      float4 xv0 = xp[0], xv1 = xp[1], xv2 = xp[2], xv3 = xp[3];
      float v[16];
      {
        float x0 = xv0.x, x1 = xv0.y, x2 = xv0.z, x3 = xv0.w;
        v[0] = fmaf(x3, w3.x, fmaf(x2, w2.x, fmaf(x1, w1.x, x0 * w0.x)));
        v[1] = fmaf(x3, w3.y, fmaf(x2, w2.y, fmaf(x1, w1.y, x0 * w0.y)));
        v[2] = fmaf(x3, w3.z, fmaf(x2, w2.z, fmaf(x1, w1.z, x0 * w0.z)));
        v[3] = fmaf(x3, w3.w, fmaf(x2, w2.w, fmaf(x1, w1.w, x0 * w0.w)));
      }
      {
        float x0 = xv1.x, x1 = xv1.y, x2 = xv1.z, x3 = xv1.w;
        v[4] = fmaf(x3, w3.x, fmaf(x2, w2.x, fmaf(x1, w1.x, x0 * w0.x)));
        v[5] = fmaf(x3, w3.y, fmaf(x2, w2.y, fmaf(x1, w1.y, x0 * w0.y)));
        v[6] = fmaf(x3, w3.z, fmaf(x2, w2.z, fmaf(x1, w1.z, x0 * w0.z)));
        v[7] = fmaf(x3, w3.w, fmaf(x2, w2.w, fmaf(x1, w1.w, x0 * w0.w)));
      }
      {
        float x0 = xv2.x, x1 = xv2.y, x2 = xv2.z, x3 = xv2.w;
        v[8]  = fmaf(x3, w3.x, fmaf(x2, w2.x, fmaf(x1, w1.x, x0 * w0.x)));
        v[9]  = fmaf(x3, w3.y, fmaf(x2, w2.y, fmaf(x1, w1.y, x0 * w0.y)));
        v[10] = fmaf(x3, w3.z, fmaf(x2, w2.z, fmaf(x1, w1.z, x0 * w0.z)));
        v[11] = fmaf(x3, w3.w, fmaf(x2, w2.w, fmaf(x1, w1.w, x0 * w0.w)));
      }
      {
        float x0 = xv3.x, x1 = xv3.y, x2 = xv3.z, x3 = xv3.w;
        v[12] = fmaf(x3, w3.x, fmaf(x2, w2.x, fmaf(x1, w1.x, x0 * w0.x)));
        v[13] = fmaf(x3, w3.y, fmaf(x2, w2.y, fmaf(x1, w1.y, x0 * w0.y)));
        v[14] = fmaf(x3, w3.z, fmaf(x2, w2.z, fmaf(x1, w1.z, x0 * w0.z)));
        v[15] = fmaf(x3, w3.w, fmaf(x2, w2.w, fmaf(x1, w1.w, x0 * w0.w)));
      }

      float af = a_sh[B];
      float wgt;
      if (pass == 0) {
        wgt = af * 0.03125f;
      } else {
        // 4 parallel chains -> dependency depth ~6 instead of 16
        float t0 = 0.f, t1 = 0.f, t2 = 0.f, t3 = 0.f;
        #pragma unroll
        for (int q = 0; q < 4; ++q) {
          float d0 = v[q*4+0] - mu[q*4+0];
          float d1 = v[q*4+1] - mu[q*4+1];
          float d2 = v[q*4+2] - mu[q*4+2];
          float d3 = v[q*4+3] - mu[q*4+3];
          if (q == 0) { t0 = d0*d0*i2s[0];  t1 = d1*d1*i2s[1];  t2 = d2*d2*i2s[2];  t3 = d3*d3*i2s[3]; }
          else {
            t0 = fmaf(d0*d0, i2s[q*4+0], t0);
            t1 = fmaf(d1*d1, i2s[q*4+1], t1);
            t2 = fmaf(d2*d2, i2s[q*4+2], t2);
            t3 = fmaf(d3*d3, i2s[q*4+3], t3);
          }
        }
        float acc = (t0 + t1) + (t2 + t3);
        float lnap = bias - acc;
        float mx = redmax32(lnap);
        float e = __expf(lnap - mx);
        float se = redsum32(e);
        float r2 = e * __builtin_amdgcn_rcpf(se);
        if (pass == 2) out[rbase + ((size_t)n * 288 + B) * 32 + c] = r2;
        wgt = r2 * af;
      }
      #pragma unroll
      for (int s = 0; s < 16; ++s) {
        float p = wgt * v[s];
        A1[s] += p;
        A2[s] = fmaf(p, v[s], A2[s]);
      }
      Ssum += wgt;
    }

    // ---- cross-half pre-reduce, then two-phase LDS reduction over 8 waves ----
    #pragma unroll
    for (int s = 0; s < 16; ++s) {
      A1[s] += __shfl_xor(A1[s], 32, 64);
      A2[s] += __shfl_xor(A2[s], 32, 64);
    }
    Ssum += __shfl_xor(Ssum, 32, 64);
    const int col = (tid >> 6) * 32 + c;
    const bool writer = (tid & 63) < 32;

    // phase A: A1 + Ssum
    if (writer) {
      #pragma unroll
      for (int s = 0; s < 16; ++s) red[s][col] = A1[s];
      red[16][col] = Ssum;
    }
    __syncthreads();
    const int s_t = tid >> 5;       // 0..15 (task index)
    const int c2 = tid & 31;
    float a1 = 0.f, ss = 0.f;
    #pragma unroll
    for (int ch = 0; ch < 8; ++ch) {
      int cl = ch * 32 + c2;
      a1 += red[s_t][cl];
      ss += red[16][cl];
    }
    float inv = __builtin_amdgcn_rcpf(ss + EPS);
    float m = a1 * inv;
    float Sc = ss * inv;
    mu_l[c2][s_t] = m;
    if (s_t == 0) S_l[c2] = ss;
    __syncthreads();

    // phase B: A2 reuses the buffer
    if (writer) {
      #pragma unroll
      for (int s = 0; s < 16; ++s) red[s][col] = A2[s];
    }
    __syncthreads();
    float a2 = 0.f;
    #pragma unroll
    for (int ch = 0; ch < 8; ++ch) a2 += red[s_t][ch * 32 + c2];
    float sg = fmaf(-m * m, 2.0f - Sc, a2 * inv) + EPS;   // sigma_sq
    i2s_l[c2][s_t] = 0.5f * __builtin_amdgcn_rcpf(sg);
    hl_l[c2][s_t] = 0.5f * __logf(sg);
    __syncthreads();

    if (tid < 32) {
      float sh = 0.f;
      #pragma unroll
      for (int s = 0; s < 16; ++s) sh += hl_l[tid][s];
      float cost = fmaf(beta_u[tid], 16.0f, sh) * S_l[tid];
      float z = LAMBDA * (beta_a[tid] - cost);
      float ao = __builtin_amdgcn_rcpf(1.0f + __expf(-z));
      aout_l[tid] = ao;
      lnao_l[tid] = __logf(ao);
    }
    __syncthreads();
  }

  // ---- outputs: row n = [mu (512) | a_out (32)], coalesced ----
  {
    int c2 = tid >> 4;
    int s = tid & 15;
    out[(size_t)n * 544 + tid] = mu_l[c2][s];
  }
  if (tid < 32) out[(size_t)n * 544 + 512 + tid] = aout_l[tid];
}

extern "C" void kernel_launch(void* const* d_in, const int* in_sizes, int n_in,
                              void* d_out, int out_size, void* d_ws, size_t ws_size,
                              hipStream_t stream) {
  const float* x  = (const float*)d_in[0];
  const float* w  = (const float*)d_in[1];
  const float* bu = (const float*)d_in[2];
  const float* ba = (const float*)d_in[3];
  float* out = (float*)d_out;
  convcaps_kernel<<<dim3(508), dim3(512), 0, stream>>>(x, w, bu, ba, out);
}

// Round 4
// 169.891 us; speedup vs baseline: 2.0881x; 2.0881x over previous
//
#include <hip/hip_runtime.h>
#include <math.h>

#define EPS 1e-8f
#define LAMBDA 1e-3f

__device__ __forceinline__ float redsum32(float v) {
  #pragma unroll
  for (int off = 16; off >= 1; off >>= 1) v += __shfl_xor(v, off, 32);
  return v;
}
__device__ __forceinline__ float redmax32(float v) {
  #pragma unroll
  for (int off = 16; off >= 1; off >>= 1) v = fmaxf(v, __shfl_xor(v, off, 32));
  return v;
}

// One block per output row n (508 rows). 512 threads = 16 chunks x 32 c.
// Thread (chunk,c) owns output capsule c for B in [chunk*18, chunk*18+18).
// su = sum_c(r*a) == a exactly (softmax sums to 1) -> fold into af=a/(a+EPS).
// Two-phase cross-chunk reduction keeps LDS at 44 KB -> 3 blocks/CU.
// launch_bounds min-waves kept at 4: forcing 6 starved the allocator to
// 40 VGPRs and spilled (R3: FETCH 10.9->633 MB, 3.4x slower). LDS is the
// intended occupancy limiter, not the register file.
__launch_bounds__(512, 4)
__global__ void convcaps_kernel(const float* __restrict__ x,
                                const float* __restrict__ wgl,
                                const float* __restrict__ beta_u,
                                const float* __restrict__ beta_a,
                                float* __restrict__ out) {
  __shared__ float xr[288][16];       // pose patches, 18 KB
  __shared__ float a_sh[288];         // a/(a+EPS)
  __shared__ float red[17][256];      // two-phase reduction scratch, 17.4 KB
  __shared__ float mu_l[32][17];      // +1 pad
  __shared__ float i2s_l[32][17];     // 1/(2*sigma)
  __shared__ float hl_l[32][17];      // 0.5*ln(sigma)
  __shared__ float S_l[32];
  __shared__ float aout_l[32];
  __shared__ float lnao_l[32];

  const int tid = threadIdx.x;
  const int n = blockIdx.x;
  const int c = tid & 31;
  const int chunk = tid >> 5;         // 0..15

  // ---- stage 9 source rows (float4): xr[B][s], a_sh[B]=a/(a+EPS) ----
  for (int idx = tid; idx < 1224; idx += 512) {   // 9 * 136 float4
    int t = idx / 136;
    int e4 = idx - t * 136;
    int g = 9 * n + t;
    int bg = g / 2286;                 // 2286 = 9*254
    int ki = (g % 2286) / 762;         // 762 = 3*254
    int owp = g % 254;
    const float4* src = reinterpret_cast<const float4*>(x) +
                        (size_t)((bg * 256 + ki + owp) * 4) * 136;
    float4 val = src[e4];
    if (e4 < 128) {
      reinterpret_cast<float4*>(&xr[0][0])[t * 128 + e4] = val;
    } else {
      val.x = val.x / (val.x + EPS);
      val.y = val.y / (val.y + EPS);
      val.z = val.z / (val.z + EPS);
      val.w = val.w / (val.w + EPS);
      reinterpret_cast<float4*>(a_sh)[t * 8 + (e4 - 128)] = val;
    }
  }
  __syncthreads();

  float A1[16], A2[16], Ssum;
  float mu[16], i2s[16];
  const size_t rbase = 276352;         // 2*254*544

  for (int pass = 0; pass < 3; ++pass) {
    #pragma unroll
    for (int s = 0; s < 16; ++s) { A1[s] = 0.f; A2[s] = 0.f; }
    Ssum = 0.f;
    float bias = 0.f;
    if (pass > 0) {
      float Hl = 0.f;
      #pragma unroll
      for (int s = 0; s < 16; ++s) {
        mu[s] = mu_l[c][s];
        i2s[s] = i2s_l[c][s];
        Hl += hl_l[c][s];
      }
      bias = lnao_l[c] - Hl;
    }

    for (int i = 0; i < 18; ++i) {
      int B = chunk * 18 + i;
      const float4* wp = reinterpret_cast<const float4*>(wgl + ((size_t)(B * 32 + c)) * 16);
      float4 w0 = wp[0], w1 = wp[1], w2 = wp[2], w3 = wp[3];
      const float4* xp = reinterpret_cast<const float4*>(&xr[B][0]);
      float4 xv0 = xp[0], xv1 = xp[1], xv2 = xp[2], xv3 = xp[3];
      float v[16];
      {
        float x0 = xv0.x, x1 = xv0.y, x2 = xv0.z, x3 = xv0.w;
        v[0] = fmaf(x3, w3.x, fmaf(x2, w2.x, fmaf(x1, w1.x, x0 * w0.x)));
        v[1] = fmaf(x3, w3.y, fmaf(x2, w2.y, fmaf(x1, w1.y, x0 * w0.y)));
        v[2] = fmaf(x3, w3.z, fmaf(x2, w2.z, fmaf(x1, w1.z, x0 * w0.z)));
        v[3] = fmaf(x3, w3.w, fmaf(x2, w2.w, fmaf(x1, w1.w, x0 * w0.w)));
      }
      {
        float x0 = xv1.x, x1 = xv1.y, x2 = xv1.z, x3 = xv1.w;
        v[4] = fmaf(x3, w3.x, fmaf(x2, w2.x, fmaf(x1, w1.x, x0 * w0.x)));
        v[5] = fmaf(x3, w3.y, fmaf(x2, w2.y, fmaf(x1, w1.y, x0 * w0.y)));
        v[6] = fmaf(x3, w3.z, fmaf(x2, w2.z, fmaf(x1, w1.z, x0 * w0.z)));
        v[7] = fmaf(x3, w3.w, fmaf(x2, w2.w, fmaf(x1, w1.w, x0 * w0.w)));
      }
      {
        float x0 = xv2.x, x1 = xv2.y, x2 = xv2.z, x3 = xv2.w;
        v[8]  = fmaf(x3, w3.x, fmaf(x2, w2.x, fmaf(x1, w1.x, x0 * w0.x)));
        v[9]  = fmaf(x3, w3.y, fmaf(x2, w2.y, fmaf(x1, w1.y, x0 * w0.y)));
        v[10] = fmaf(x3, w3.z, fmaf(x2, w2.z, fmaf(x1, w1.z, x0 * w0.z)));
        v[11] = fmaf(x3, w3.w, fmaf(x2, w2.w, fmaf(x1, w1.w, x0 * w0.w)));
      }
      {
        float x0 = xv3.x, x1 = xv3.y, x2 = xv3.z, x3 = xv3.w;
        v[12] = fmaf(x3, w3.x, fmaf(x2, w2.x, fmaf(x1, w1.x, x0 * w0.x)));
        v[13] = fmaf(x3, w3.y, fmaf(x2, w2.y, fmaf(x1, w1.y, x0 * w0.y)));
        v[14] = fmaf(x3, w3.z, fmaf(x2, w2.z, fmaf(x1, w1.z, x0 * w0.z)));
        v[15] = fmaf(x3, w3.w, fmaf(x2, w2.w, fmaf(x1, w1.w, x0 * w0.w)));
      }

      float af = a_sh[B];
      float wgt;
      if (pass == 0) {
        wgt = af * 0.03125f;
      } else {
        // 4 parallel chains -> dependency depth ~6 instead of 16
        float t0 = 0.f, t1 = 0.f, t2 = 0.f, t3 = 0.f;
        #pragma unroll
        for (int q = 0; q < 4; ++q) {
          float d0 = v[q*4+0] - mu[q*4+0];
          float d1 = v[q*4+1] - mu[q*4+1];
          float d2 = v[q*4+2] - mu[q*4+2];
          float d3 = v[q*4+3] - mu[q*4+3];
          if (q == 0) { t0 = d0*d0*i2s[0];  t1 = d1*d1*i2s[1];  t2 = d2*d2*i2s[2];  t3 = d3*d3*i2s[3]; }
          else {
            t0 = fmaf(d0*d0, i2s[q*4+0], t0);
            t1 = fmaf(d1*d1, i2s[q*4+1], t1);
            t2 = fmaf(d2*d2, i2s[q*4+2], t2);
            t3 = fmaf(d3*d3, i2s[q*4+3], t3);
          }
        }
        float acc = (t0 + t1) + (t2 + t3);
        float lnap = bias - acc;
        float mx = redmax32(lnap);
        float e = __expf(lnap - mx);
        float se = redsum32(e);
        float r2 = e * __builtin_amdgcn_rcpf(se);
        if (pass == 2) out[rbase + ((size_t)n * 288 + B) * 32 + c] = r2;
        wgt = r2 * af;
      }
      #pragma unroll
      for (int s = 0; s < 16; ++s) {
        float p = wgt * v[s];
        A1[s] += p;
        A2[s] = fmaf(p, v[s], A2[s]);
      }
      Ssum += wgt;
    }

    // ---- cross-half pre-reduce, then two-phase LDS reduction over 8 waves ----
    #pragma unroll
    for (int s = 0; s < 16; ++s) {
      A1[s] += __shfl_xor(A1[s], 32, 64);
      A2[s] += __shfl_xor(A2[s], 32, 64);
    }
    Ssum += __shfl_xor(Ssum, 32, 64);
    const int col = (tid >> 6) * 32 + c;
    const bool writer = (tid & 63) < 32;

    // phase A: A1 + Ssum
    if (writer) {
      #pragma unroll
      for (int s = 0; s < 16; ++s) red[s][col] = A1[s];
      red[16][col] = Ssum;
    }
    __syncthreads();
    const int s_t = tid >> 5;       // 0..15 (task index)
    const int c2 = tid & 31;
    float a1 = 0.f, ss = 0.f;
    #pragma unroll
    for (int ch = 0; ch < 8; ++ch) {
      int cl = ch * 32 + c2;
      a1 += red[s_t][cl];
      ss += red[16][cl];
    }
    float inv = __builtin_amdgcn_rcpf(ss + EPS);
    float m = a1 * inv;
    float Sc = ss * inv;
    mu_l[c2][s_t] = m;
    if (s_t == 0) S_l[c2] = ss;
    __syncthreads();

    // phase B: A2 reuses the buffer
    if (writer) {
      #pragma unroll
      for (int s = 0; s < 16; ++s) red[s][col] = A2[s];
    }
    __syncthreads();
    float a2 = 0.f;
    #pragma unroll
    for (int ch = 0; ch < 8; ++ch) a2 += red[s_t][ch * 32 + c2];
    float sg = fmaf(-m * m, 2.0f - Sc, a2 * inv) + EPS;   // sigma_sq
    i2s_l[c2][s_t] = 0.5f * __builtin_amdgcn_rcpf(sg);
    hl_l[c2][s_t] = 0.5f * __logf(sg);
    __syncthreads();

    if (tid < 32) {
      float sh = 0.f;
      #pragma unroll
      for (int s = 0; s < 16; ++s) sh += hl_l[tid][s];
      float cost = fmaf(beta_u[tid], 16.0f, sh) * S_l[tid];
      float z = LAMBDA * (beta_a[tid] - cost);
      float ao = __builtin_amdgcn_rcpf(1.0f + __expf(-z));
      aout_l[tid] = ao;
      lnao_l[tid] = __logf(ao);
    }
    __syncthreads();
  }

  // ---- outputs: row n = [mu (512) | a_out (32)], coalesced ----
  {
    int c2 = tid >> 4;
    int s = tid & 15;
    out[(size_t)n * 544 + tid] = mu_l[c2][s];
  }
  if (tid < 32) out[(size_t)n * 544 + 512 + tid] = aout_l[tid];
}

extern "C" void kernel_launch(void* const* d_in, const int* in_sizes, int n_in,
                              void* d_out, int out_size, void* d_ws, size_t ws_size,
                              hipStream_t stream) {
  const float* x  = (const float*)d_in[0];
  const float* w  = (const float*)d_in[1];
  const float* bu = (const float*)d_in[2];
  const float* ba = (const float*)d_in[3];
  float* out = (float*)d_out;
  convcaps_kernel<<<dim3(508), dim3(512), 0, stream>>>(x, w, bu, ba, out);
}